// Round 2
// baseline (693.212 us; speedup 1.0000x reference)
//
#include <hip/hip_runtime.h>
#include <hip/hip_bf16.h>
#include <math.h>

constexpr int S_LEN  = 256;
constexpr int T_LEN  = 2560;
constexpr int D_IN   = 512;
constexpr int DK     = 64;
constexpr int B_N    = 2;
constexpr int ROWS_A = 8;
constexpr int QB     = 4;      // query rows per attention block

__device__ __forceinline__ float wave_reduce_sum(float v) {
#pragma unroll
    for (int off = 32; off > 0; off >>= 1) v += __shfl_down(v, off);
    return v;
}

// ---------------------------------------------------------------------------
// Kernel A: region-wise LayerNorm + QKV projection. (unchanged from R1)
// ---------------------------------------------------------------------------
__global__ __launch_bounds__(256) void ln_qkv_kernel(
    const float* __restrict__ x,
    const float* __restrict__ w_q,  const float* __restrict__ w_k,  const float* __restrict__ w_v,
    const float* __restrict__ w_qs, const float* __restrict__ w_ks, const float* __restrict__ w_vs,
    const float* __restrict__ w_qe, const float* __restrict__ w_ke, const float* __restrict__ w_ve,
    const float* __restrict__ g_m,  const float* __restrict__ b_m,
    const float* __restrict__ g_s,  const float* __restrict__ b_s,
    const float* __restrict__ g_e,  const float* __restrict__ b_e,
    float* __restrict__ q_out, float* __restrict__ kT_out, float* __restrict__ v_out)
{
    const int tid  = threadIdx.x;
    const int row0 = blockIdx.x * ROWS_A;
    const int b    = row0 / T_LEN;
    const int t0   = row0 % T_LEN;

    __shared__ float xn[ROWS_A][D_IN];
    __shared__ float red[8];

    const float *gv, *bv, *WQ, *WK, *WV;
    if (t0 < S_LEN)              { gv = g_s; bv = b_s; WQ = w_qs; WK = w_ks; WV = w_vs; }
    else if (t0 < T_LEN - S_LEN) { gv = g_m; bv = b_m; WQ = w_q;  WK = w_k;  WV = w_v;  }
    else                         { gv = g_e; bv = b_e; WQ = w_qe; WK = w_ke; WV = w_ve; }

    for (int r = 0; r < ROWS_A; ++r) {
        const float* xr = x + (size_t)(row0 + r) * D_IN;
        float a0 = xr[tid], a1 = xr[tid + 256];
        float s = wave_reduce_sum(a0 + a1);
        __syncthreads();
        if ((tid & 63) == 0) red[tid >> 6] = s;
        __syncthreads();
        float mean = (red[0] + red[1] + red[2] + red[3]) * (1.0f / D_IN);
        float d0 = a0 - mean, d1 = a1 - mean;
        float sq = wave_reduce_sum(d0 * d0 + d1 * d1);
        __syncthreads();
        if ((tid & 63) == 0) red[tid >> 6] = sq;
        __syncthreads();
        float var = (red[0] + red[1] + red[2] + red[3]) * (1.0f / D_IN);
        float inv = rsqrtf(var + 1e-5f);
        xn[r][tid]       = d0 * inv * gv[tid]       + bv[tid];
        xn[r][tid + 256] = d1 * inv * gv[tid + 256] + bv[tid + 256];
    }
    __syncthreads();

    if (tid < 192) {
        const int mat = tid >> 6, col = tid & 63;
        const float* W = (mat == 0) ? WQ : (mat == 1) ? WK : WV;
        float acc[ROWS_A];
#pragma unroll
        for (int r = 0; r < ROWS_A; ++r) acc[r] = 0.f;
        for (int d = 0; d < D_IN; ++d) {
            float wv = W[d * DK + col];
#pragma unroll
            for (int r = 0; r < ROWS_A; ++r) acc[r] += xn[r][d] * wv;
        }
#pragma unroll
        for (int r = 0; r < ROWS_A; ++r) {
            int row = row0 + r;
            if (mat == 0)       q_out[(size_t)row * DK + col] = acc[r];
            else if (mat == 1)  kT_out[((size_t)b * DK + col) * T_LEN + (t0 + r)] = acc[r];
            else                v_out[(size_t)row * DK + col] = acc[r];
        }
    }
}

// ---------------------------------------------------------------------------
// Kernel B: QB=4 query rows per block; k/cope/v loads amortized across rows.
// ---------------------------------------------------------------------------
template<int W> struct VecW;
template<> struct VecW<4> { using T = float4; };
template<> struct VecW<2> { using T = float2; };

template<int W>
__device__ __forceinline__ void pass1_sweep(
    int s, const float* __restrict__ kTb, const float* __restrict__ cope,
    const float (*qs)[DK], float (*slog)[T_LEN], __hip_bfloat16 (*sli)[T_LEN])
{
    using VT = typename VecW<W>::T;
    float aL[QB][W], aM[QB][W];
#pragma unroll
    for (int r = 0; r < QB; ++r)
#pragma unroll
        for (int w = 0; w < W; ++w) { aL[r][w] = 0.f; aM[r][w] = 0.f; }

#pragma unroll
    for (int d0 = 0; d0 < DK; d0 += 4) {
        float kv[4][W], cv[4][W];
#pragma unroll
        for (int j = 0; j < 4; ++j) {
            VT kt = *(const VT*)&kTb[(size_t)(d0 + j) * T_LEN + s];
            VT ct = *(const VT*)&cope[(size_t)(d0 + j) * T_LEN + s];
            *(VT*)&kv[j][0] = kt;
            *(VT*)&cv[j][0] = ct;
        }
#pragma unroll
        for (int r = 0; r < QB; ++r) {
            float qarr[4];
            *(float4*)qarr = *(const float4*)&qs[r][d0];
#pragma unroll
            for (int j = 0; j < 4; ++j) {
                float qd = qarr[j];
#pragma unroll
                for (int w = 0; w < W; ++w) {
                    aL[r][w] = fmaf(qd, kv[j][w], aL[r][w]);
                    aM[r][w] = fmaf(qd, cv[j][w], aM[r][w]);
                }
            }
        }
    }
#pragma unroll
    for (int r = 0; r < QB; ++r) {
        *(VT*)&slog[r][s] = *(VT*)&aL[r][0];
#pragma unroll
        for (int w = 0; w < W; ++w) sli[r][s + w] = __float2bfloat16(aM[r][w]);
    }
}

__global__ __launch_bounds__(256) void attn_kernel(
    const float* __restrict__ q_in,
    const float* __restrict__ kT,
    const float* __restrict__ v_in,
    const float* __restrict__ cope,
    float* __restrict__ out)
{
    const int tid = threadIdx.x;

    // XCD-aware swizzle: 1280 blocks = 8 XCDs x 160 slots (assumes bid%8->XCD).
    // XCDs 0-3 own batch 0, XCDs 4-7 batch 1: per-XCD L2 working set ~3.9MB.
    const int bid  = blockIdx.x;
    const int xcd  = bid & 7;
    const int slot = bid >> 3;
    const int b    = xcd >> 2;
    const int tile = (xcd & 3) * (T_LEN / QB / 4) + slot;  // 160 tiles per xcd
    const int t0   = tile * QB;                            // row within batch

    __shared__ float          slog[QB][T_LEN];   // 40 KB: logits -> p
    __shared__ __hip_bfloat16 sli [QB][T_LEN];   // 20 KB: li for CoPE gather
    __shared__ float          qs  [QB][DK];      //  1 KB
    __shared__ float4         sscan[256];        //  4 KB
    __shared__ float          red[2][4][QB];     // wave partial max/sum

    // stage q
    {
        int r = tid >> 6, d = tid & 63;
        qs[r][d] = q_in[((size_t)(b * T_LEN + t0 + r)) * DK + d];
    }
    __syncthreads();

    const float* kTb = kT + (size_t)b * DK * T_LEN;

    // ---- pass 1: logits + li for all 4 rows, vectorized over s -------------
    pass1_sweep<4>(tid * 4,        kTb, cope, qs, slog, sli);
    pass1_sweep<4>(1024 + tid * 4, kTb, cope, qs, slog, sli);
    pass1_sweep<2>(2048 + tid * 2, kTb, cope, qs, slog, sli);
    __syncthreads();

    // ---- gate prefix scan (4 rows folded into one float4 scan) -------------
    constexpr int CH = T_LEN / 256;  // 10
    const int s0 = tid * CH;
    float lsum[QB];
#pragma unroll
    for (int r = 0; r < QB; ++r) {
        float s = 0.f;
#pragma unroll
        for (int i = 0; i < CH; ++i)
            s += 1.0f / (1.0f + __expf(-slog[r][s0 + i]));
        lsum[r] = s;
    }
    sscan[tid] = make_float4(lsum[0], lsum[1], lsum[2], lsum[3]);
    __syncthreads();
    for (int off = 1; off < 256; off <<= 1) {
        float4 cur = sscan[tid];
        float4 add = (tid >= off) ? sscan[tid - off] : make_float4(0.f, 0.f, 0.f, 0.f);
        __syncthreads();
        cur.x += add.x; cur.y += add.y; cur.z += add.z; cur.w += add.w;
        sscan[tid] = cur;
        __syncthreads();
    }
    const float4 inc = sscan[tid];
    const float4 tot = sscan[255];
    float run[QB]   = { inc.x - lsum[0], inc.y - lsum[1], inc.z - lsum[2], inc.w - lsum[3] };
    float total[QB] = { tot.x, tot.y, tot.z, tot.w };

    // ---- CoPE bias + causal mask; att logits in registers ------------------
    float att[QB][CH];
    float lmax[QB];
#pragma unroll
    for (int r = 0; r < QB; ++r) {
        float mx = -INFINITY;
        float rn = run[r];
        const int trow = t0 + r;
#pragma unroll
        for (int i = 0; i < CH; ++i) {
            int s = s0 + i;
            float lg  = slog[r][s];
            float gg  = 1.0f / (1.0f + __expf(-lg));
            float pos = total[r] - rn;
            rn += gg;
            pos = fminf(pos, (float)(T_LEN - 1));
            float pf = floorf(pos);
            float w  = pos - pf;
            int ipf  = (int)pf;
            int ipc  = (int)ceilf(pos);
            float bias = __bfloat162float(sli[r][ipc]) * w
                       + __bfloat162float(sli[r][ipf]) * (1.0f - w);
            float al = lg * 0.125f + bias;
            if (s > trow) al = -INFINITY;
            att[r][i] = al;
            mx = fmaxf(mx, al);
        }
        lmax[r] = mx;
    }

    // ---- block max per row -------------------------------------------------
#pragma unroll
    for (int r = 0; r < QB; ++r) {
        float m = lmax[r];
#pragma unroll
        for (int off = 32; off > 0; off >>= 1) m = fmaxf(m, __shfl_down(m, off));
        if ((tid & 63) == 0) red[0][tid >> 6][r] = m;
    }
    __syncthreads();
    float bmax[QB];
#pragma unroll
    for (int r = 0; r < QB; ++r)
        bmax[r] = fmaxf(fmaxf(red[0][0][r], red[0][1][r]),
                        fmaxf(red[0][2][r], red[0][3][r]));

    // ---- exp, store p (unnormalized) back into slog, reduce denom ----------
#pragma unroll
    for (int r = 0; r < QB; ++r) {
        float es = 0.f;
#pragma unroll
        for (int i = 0; i < CH; ++i) {
            int s   = s0 + i;
            float e = __expf(att[r][i] - bmax[r]);  // exp(-inf)=0 handles mask
            slog[r][s] = e;
            es += e;
        }
#pragma unroll
        for (int off = 32; off > 0; off >>= 1) es += __shfl_down(es, off);
        if ((tid & 63) == 0) red[1][tid >> 6][r] = es;
    }
    __syncthreads();
    float rdenom[QB];
#pragma unroll
    for (int r = 0; r < QB; ++r)
        rdenom[r] = 1.0f / (red[1][0][r] + red[1][1][r] + red[1][2][r] + red[1][3][r]);

    // ---- PV: v loads shared across rows; p read via uniform b128 -----------
    const int d   = tid & 63;
    const int grp = tid >> 6;
    const float* vb = v_in + (size_t)b * T_LEN * DK;
    float acc[QB] = {0.f, 0.f, 0.f, 0.f};
    const int t_hi = t0 + QB - 1;
    for (int base = 0; base <= t_hi; base += 16) {
        int sblk = base + grp * 4;
        if (sblk <= t_hi) {
            float pr[QB][4];
#pragma unroll
            for (int r = 0; r < QB; ++r)
                *(float4*)&pr[r][0] = *(const float4*)&slog[r][sblk];
#pragma unroll
            for (int j = 0; j < 4; ++j) {
                float vval = vb[(size_t)(sblk + j) * DK + d];
#pragma unroll
                for (int r = 0; r < QB; ++r)
                    acc[r] = fmaf(pr[r][j], vval, acc[r]);
            }
        }
    }
    __syncthreads();
    sscan[tid] = make_float4(acc[0], acc[1], acc[2], acc[3]);
    __syncthreads();
    if (grp == 0) {
        float4 a0 = sscan[tid], a1 = sscan[tid + 64],
               a2 = sscan[tid + 128], a3 = sscan[tid + 192];
        float o[QB] = { (a0.x + a1.x) + (a2.x + a3.x),
                        (a0.y + a1.y) + (a2.y + a3.y),
                        (a0.z + a1.z) + (a2.z + a3.z),
                        (a0.w + a1.w) + (a2.w + a3.w) };
#pragma unroll
        for (int r = 0; r < QB; ++r)
            out[((size_t)(b * T_LEN + t0 + r)) * DK + d] = o[r] * rdenom[r];
    }
}

extern "C" void kernel_launch(void* const* d_in, const int* in_sizes, int n_in,
                              void* d_out, int out_size, void* d_ws, size_t ws_size,
                              hipStream_t stream)
{
    const float* x    = (const float*)d_in[0];
    const float* w_q  = (const float*)d_in[1];
    const float* w_k  = (const float*)d_in[2];
    const float* w_v  = (const float*)d_in[3];
    const float* w_qs = (const float*)d_in[4];
    const float* w_ks = (const float*)d_in[5];
    const float* w_vs = (const float*)d_in[6];
    const float* w_qe = (const float*)d_in[7];
    const float* w_ke = (const float*)d_in[8];
    const float* w_ve = (const float*)d_in[9];
    const float* g_m  = (const float*)d_in[10];
    const float* b_m  = (const float*)d_in[11];
    const float* g_s  = (const float*)d_in[12];
    const float* b_s  = (const float*)d_in[13];
    const float* g_e  = (const float*)d_in[14];
    const float* b_e  = (const float*)d_in[15];
    const float* cope = (const float*)d_in[16];

    float* q_ws  = (float*)d_ws;
    float* kT_ws = q_ws  + (size_t)B_N * T_LEN * DK;
    float* v_ws  = kT_ws + (size_t)B_N * T_LEN * DK;

    ln_qkv_kernel<<<(B_N * T_LEN) / ROWS_A, 256, 0, stream>>>(
        x, w_q, w_k, w_v, w_qs, w_ks, w_vs, w_qe, w_ke, w_ve,
        g_m, b_m, g_s, b_s, g_e, b_e,
        q_ws, kT_ws, v_ws);

    attn_kernel<<<(B_N * T_LEN) / QB, 256, 0, stream>>>(
        q_ws, kT_ws, v_ws, cope, (float*)d_out);
}

// Round 4
// 175.827 us; speedup vs baseline: 3.9426x; 3.9426x over previous
//
#include <hip/hip_runtime.h>
#include <hip/hip_bf16.h>
#include <math.h>

using short8 = __attribute__((ext_vector_type(8))) short;
using f32x4  = __attribute__((ext_vector_type(4))) float;

constexpr int S_LEN  = 256;
constexpr int T      = 2560;
constexpr int D_IN   = 512;
constexpr int DK     = 64;
constexpr int B_N    = 2;
constexpr int ROWS_A = 16;
constexpr int SS     = 16;     // split-K chunks for PV (T/SS = 160 per chunk)

__device__ __forceinline__ float wave_reduce_sum(float v) {
#pragma unroll
    for (int off = 32; off > 0; off >>= 1) v += __shfl_down(v, off);
    return v;
}

// ---------------------------------------------------------------------------
// Kernel A: region-wise LayerNorm + QKV projection (both batches, once).
// Emits split-bf16 q,k (natural T x 64) and bf16 vT (64 x T).
// ---------------------------------------------------------------------------
__global__ __launch_bounds__(256) void ln_qkv_kernel(
    const float* __restrict__ x,
    const float* __restrict__ w_q,  const float* __restrict__ w_k,  const float* __restrict__ w_v,
    const float* __restrict__ w_qs, const float* __restrict__ w_ks, const float* __restrict__ w_vs,
    const float* __restrict__ w_qe, const float* __restrict__ w_ke, const float* __restrict__ w_ve,
    const float* __restrict__ g_m,  const float* __restrict__ b_m,
    const float* __restrict__ g_s,  const float* __restrict__ b_s,
    const float* __restrict__ g_e,  const float* __restrict__ b_e,
    __hip_bfloat16* __restrict__ qh, __hip_bfloat16* __restrict__ ql,
    __hip_bfloat16* __restrict__ kh, __hip_bfloat16* __restrict__ kl,
    __hip_bfloat16* __restrict__ vT)
{
    const int tid  = threadIdx.x;
    const int row0 = blockIdx.x * ROWS_A;
    const int b    = row0 / T;
    const int t0   = row0 % T;

    __shared__ float xn[ROWS_A][D_IN];
    __shared__ float red[8];

    const float *gv, *bv, *WQ, *WK, *WV;
    if (t0 < S_LEN)          { gv = g_s; bv = b_s; WQ = w_qs; WK = w_ks; WV = w_vs; }
    else if (t0 < T - S_LEN) { gv = g_m; bv = b_m; WQ = w_q;  WK = w_k;  WV = w_v;  }
    else                     { gv = g_e; bv = b_e; WQ = w_qe; WK = w_ke; WV = w_ve; }

    for (int r = 0; r < ROWS_A; ++r) {
        const float* xr = x + (size_t)(row0 + r) * D_IN;
        float a0 = xr[tid], a1 = xr[tid + 256];
        float s = wave_reduce_sum(a0 + a1);
        __syncthreads();
        if ((tid & 63) == 0) red[tid >> 6] = s;
        __syncthreads();
        float mean = (red[0] + red[1] + red[2] + red[3]) * (1.0f / D_IN);
        float d0 = a0 - mean, d1 = a1 - mean;
        float sq = wave_reduce_sum(d0 * d0 + d1 * d1);
        __syncthreads();
        if ((tid & 63) == 0) red[tid >> 6] = sq;
        __syncthreads();
        float var = (red[0] + red[1] + red[2] + red[3]) * (1.0f / D_IN);
        float inv = rsqrtf(var + 1e-5f);
        xn[r][tid]       = d0 * inv * gv[tid]       + bv[tid];
        xn[r][tid + 256] = d1 * inv * gv[tid + 256] + bv[tid + 256];
    }
    __syncthreads();

    if (tid < 192) {
        const int mat = tid >> 6, col = tid & 63;
        const float* W = (mat == 0) ? WQ : (mat == 1) ? WK : WV;
        float acc[ROWS_A];
#pragma unroll
        for (int r = 0; r < ROWS_A; ++r) acc[r] = 0.f;
        for (int d = 0; d < D_IN; ++d) {
            float wv = W[d * DK + col];
#pragma unroll
            for (int r = 0; r < ROWS_A; ++r) acc[r] += xn[r][d] * wv;
        }
#pragma unroll
        for (int r = 0; r < ROWS_A; ++r) {
            const int row = row0 + r;
            float f = acc[r];
            __hip_bfloat16 h  = __float2bfloat16(f);
            float hf          = __bfloat162float(h);
            __hip_bfloat16 lo = __float2bfloat16(f - hf);
            if (mat == 0)      { qh[(size_t)row * DK + col] = h; ql[(size_t)row * DK + col] = lo; }
            else if (mat == 1) { kh[(size_t)row * DK + col] = h; kl[(size_t)row * DK + col] = lo; }
            else               { vT[((size_t)b * DK + col) * T + (t0 + r)] = h; }
        }
    }
}

// cope (DK x T f32) -> copeT (T x DK bf16)
__global__ __launch_bounds__(256) void prep_cope_kernel(
    const float* __restrict__ cope, __hip_bfloat16* __restrict__ copeT)
{
    const int i = blockIdx.x * 256 + threadIdx.x;
    const int m = i >> 6, d = i & 63;
    copeT[i] = __float2bfloat16(cope[(size_t)d * T + m]);
}

// ---------------------------------------------------------------------------
// GEMM1 (per batch b, chunk of TC rows starting at t_off):
//   logits_c[tl, s] = q.k (split-bf16, 3 passes ~ f32)
//   li_c[tl, s]     = q.cope (bf16)
// Block tile 128(t) x 64(s); 4 waves 2x2; fragments straight from global.
// ---------------------------------------------------------------------------
__global__ __launch_bounds__(256) void gemm1_kernel(
    const __hip_bfloat16* __restrict__ qh, const __hip_bfloat16* __restrict__ ql,
    const __hip_bfloat16* __restrict__ kh, const __hip_bfloat16* __restrict__ kl,
    const __hip_bfloat16* __restrict__ copeT,
    float* __restrict__ logits_c, __hip_bfloat16* __restrict__ li_c,
    int b, int t_off)
{
    constexpr int TS = T / 64;  // 40
    const int ti  = blockIdx.x / TS, si = blockIdx.x % TS;
    const int t0  = ti * 128, s0 = si * 64;   // t0 local to chunk
    const int tid = threadIdx.x, lane = tid & 63, wid = tid >> 6;
    const int wm  = wid >> 1, wn = wid & 1;
    const int fr  = lane & 15, k8 = (lane >> 4) * 8;
    const size_t qb = (size_t)b * T * DK;

    short8 ah[4][2], al[4][2];
#pragma unroll
    for (int mf = 0; mf < 4; ++mf)
#pragma unroll
        for (int ks = 0; ks < 2; ++ks) {
            size_t off = qb + (size_t)(t_off + t0 + wm * 64 + mf * 16 + fr) * DK + ks * 32 + k8;
            ah[mf][ks] = *(const short8*)(qh + off);
            al[mf][ks] = *(const short8*)(ql + off);
        }
    short8 bh[2][2], bl[2][2], bc[2][2];
#pragma unroll
    for (int nf = 0; nf < 2; ++nf)
#pragma unroll
        for (int ks = 0; ks < 2; ++ks) {
            size_t off = (size_t)(s0 + wn * 32 + nf * 16 + fr) * DK + ks * 32 + k8;
            bh[nf][ks] = *(const short8*)(kh + qb + off);
            bl[nf][ks] = *(const short8*)(kl + qb + off);
            bc[nf][ks] = *(const short8*)(copeT + off);
        }

    f32x4 accL[4][2], accM[4][2];
#pragma unroll
    for (int mf = 0; mf < 4; ++mf)
#pragma unroll
        for (int nf = 0; nf < 2; ++nf) {
            accL[mf][nf] = (f32x4){0.f, 0.f, 0.f, 0.f};
            accM[mf][nf] = (f32x4){0.f, 0.f, 0.f, 0.f};
        }

#pragma unroll
    for (int mf = 0; mf < 4; ++mf)
#pragma unroll
        for (int nf = 0; nf < 2; ++nf)
#pragma unroll
            for (int ks = 0; ks < 2; ++ks) {
                accL[mf][nf] = __builtin_amdgcn_mfma_f32_16x16x32_bf16(ah[mf][ks], bh[nf][ks], accL[mf][nf], 0, 0, 0);
                accL[mf][nf] = __builtin_amdgcn_mfma_f32_16x16x32_bf16(ah[mf][ks], bl[nf][ks], accL[mf][nf], 0, 0, 0);
                accL[mf][nf] = __builtin_amdgcn_mfma_f32_16x16x32_bf16(al[mf][ks], bh[nf][ks], accL[mf][nf], 0, 0, 0);
                accM[mf][nf] = __builtin_amdgcn_mfma_f32_16x16x32_bf16(ah[mf][ks], bc[nf][ks], accM[mf][nf], 0, 0, 0);
            }

    const int r4 = (lane >> 4) * 4;
#pragma unroll
    for (int mf = 0; mf < 4; ++mf)
#pragma unroll
        for (int nf = 0; nf < 2; ++nf) {
            const int cg = s0 + wn * 32 + nf * 16 + fr;
#pragma unroll
            for (int j = 0; j < 4; ++j) {
                const int rl = t0 + wm * 64 + mf * 16 + r4 + j;   // local row
                const size_t o = (size_t)rl * T + cg;
                logits_c[o] = accL[mf][nf][j];
                li_c[o]     = __float2bfloat16(accM[mf][nf][j]);
            }
        }
}

// ---------------------------------------------------------------------------
// Phase 2 (per chunk): gates -> suffix-sum -> CoPE bias -> softmax.
// Rewrites logits_c row IN PLACE with normalized p (f32).
// ---------------------------------------------------------------------------
__global__ __launch_bounds__(256) void phase2_kernel(
    float* __restrict__ logits_c, const __hip_bfloat16* __restrict__ li_c,
    int t_off)
{
    const int tid = threadIdx.x;
    const int rl  = blockIdx.x;        // local row
    const int t   = t_off + rl;        // global causal position

    __shared__ float          slog[T];
    __shared__ __hip_bfloat16 sli[T];
    __shared__ float          sscan[256];
    __shared__ float          red[8];

    float*                lrow  = logits_c + (size_t)rl * T;
    const __hip_bfloat16* lirow = li_c     + (size_t)rl * T;
#pragma unroll
    for (int i = 0; i < 10; ++i) slog[i * 256 + tid] = lrow[i * 256 + tid];
#pragma unroll
    for (int i = 0; i < 10; ++i) sli[i * 256 + tid] = lirow[i * 256 + tid];
    __syncthreads();

    constexpr int CH = T / 256;  // 10
    const int s0 = tid * CH;
    float g[CH];
    float lsum = 0.f;
#pragma unroll
    for (int i = 0; i < CH; ++i) {
        g[i] = 1.0f / (1.0f + __expf(-slog[s0 + i]));
        lsum += g[i];
    }
    sscan[tid] = lsum;
    __syncthreads();
    for (int off = 1; off < 256; off <<= 1) {
        float add = (tid >= off) ? sscan[tid - off] : 0.f;
        __syncthreads();
        sscan[tid] += add;
        __syncthreads();
    }
    const float total = sscan[255];
    float run = sscan[tid] - lsum;

    float att[CH];
    float lmax = -INFINITY;
#pragma unroll
    for (int i = 0; i < CH; ++i) {
        int s = s0 + i;
        float pos = total - run;
        run += g[i];
        pos = fminf(pos, (float)(T - 1));
        float pf = floorf(pos);
        float w  = pos - pf;
        int ipf  = (int)pf;
        int ipc  = (int)ceilf(pos);
        float bias = __bfloat162float(sli[ipc]) * w
                   + __bfloat162float(sli[ipf]) * (1.0f - w);
        float al = slog[s] * 0.125f + bias;
        if (s > t) al = -INFINITY;
        att[i] = al;
        lmax = fmaxf(lmax, al);
    }

#pragma unroll
    for (int off = 32; off > 0; off >>= 1) lmax = fmaxf(lmax, __shfl_down(lmax, off));
    __syncthreads();
    if ((tid & 63) == 0) red[tid >> 6] = lmax;
    __syncthreads();
    const float bmax = fmaxf(fmaxf(red[0], red[1]), fmaxf(red[2], red[3]));

    float e[CH];
    float esum = 0.f;
#pragma unroll
    for (int i = 0; i < CH; ++i) {
        e[i] = __expf(att[i] - bmax);   // exp(-inf)=0 covers causal mask
        esum += e[i];
    }
#pragma unroll
    for (int off = 32; off > 0; off >>= 1) esum += __shfl_down(esum, off);
    __syncthreads();
    if ((tid & 63) == 0) red[4 + (tid >> 6)] = esum;
    __syncthreads();
    const float rden = 1.0f / (red[4] + red[5] + red[6] + red[7]);

#pragma unroll
    for (int i = 0; i < CH; ++i)
        lrow[s0 + i] = e[i] * rden;     // p (f32), in place
}

// ---------------------------------------------------------------------------
// GEMM2 (per chunk): out_part = P @ V, split-K into SS chunks of 160.
// P read as f32, split into hi/lo bf16 in-register (2-pass MFMA).
// ---------------------------------------------------------------------------
__global__ __launch_bounds__(256) void gemm2_kernel(
    const float* __restrict__ p_c, const __hip_bfloat16* __restrict__ vT,
    float* __restrict__ part, int b, int TC)
{
    const int ti  = blockIdx.x / SS, sc = blockIdx.x % SS;
    const int t0  = ti * 128;
    const int sb  = sc * (T / SS);          // 160-wide K chunk
    const int tid = threadIdx.x, lane = tid & 63, wid = tid >> 6;
    const int wm  = wid >> 1, wn = wid & 1;
    const int fr  = lane & 15, k8 = (lane >> 4) * 8;
    const size_t vb = (size_t)b * DK * T;

    f32x4 acc[4][2];
#pragma unroll
    for (int mf = 0; mf < 4; ++mf)
#pragma unroll
        for (int nf = 0; nf < 2; ++nf) acc[mf][nf] = (f32x4){0.f, 0.f, 0.f, 0.f};

    for (int ks = 0; ks < (T / SS) / 32; ++ks) {   // 5 k-steps
        const int s = sb + ks * 32 + k8;
        short8 a_h[4], a_l[4], bv[2];
#pragma unroll
        for (int mf = 0; mf < 4; ++mf) {
            const float* pp = p_c + (size_t)(t0 + wm * 64 + mf * 16 + fr) * T + s;
            short hh[8], ll[8];
#pragma unroll
            for (int j = 0; j < 8; ++j) {
                float p = pp[j];
                __hip_bfloat16 h  = __float2bfloat16(p);
                __hip_bfloat16 lo = __float2bfloat16(p - __bfloat162float(h));
                hh[j] = *(short*)&h;
                ll[j] = *(short*)&lo;
            }
            a_h[mf] = (short8){hh[0],hh[1],hh[2],hh[3],hh[4],hh[5],hh[6],hh[7]};
            a_l[mf] = (short8){ll[0],ll[1],ll[2],ll[3],ll[4],ll[5],ll[6],ll[7]};
        }
#pragma unroll
        for (int nf = 0; nf < 2; ++nf)
            bv[nf] = *(const short8*)(vT + vb + (size_t)(wn * 32 + nf * 16 + fr) * T + s);
#pragma unroll
        for (int mf = 0; mf < 4; ++mf)
#pragma unroll
            for (int nf = 0; nf < 2; ++nf) {
                acc[mf][nf] = __builtin_amdgcn_mfma_f32_16x16x32_bf16(a_h[mf], bv[nf], acc[mf][nf], 0, 0, 0);
                acc[mf][nf] = __builtin_amdgcn_mfma_f32_16x16x32_bf16(a_l[mf], bv[nf], acc[mf][nf], 0, 0, 0);
            }
    }

    const int r4 = (lane >> 4) * 4;
#pragma unroll
    for (int mf = 0; mf < 4; ++mf)
#pragma unroll
        for (int nf = 0; nf < 2; ++nf) {
            const int cg = wn * 32 + nf * 16 + fr;
#pragma unroll
            for (int j = 0; j < 4; ++j) {
                const int rl = t0 + wm * 64 + mf * 16 + r4 + j;
                part[((size_t)sc * TC + rl) * DK + cg] = acc[mf][nf][j];
            }
        }
}

__global__ __launch_bounds__(256) void reduce_kernel(
    const float* __restrict__ part, float* __restrict__ out,
    int b, int t_off, int TC)
{
    const size_t i = (size_t)blockIdx.x * 256 + threadIdx.x;  // TC*DK total
    float s = 0.f;
    for (int sc = 0; sc < SS; ++sc) s += part[(size_t)sc * TC * DK + i];
    out[((size_t)b * T + t_off) * DK + i] = s;
}

extern "C" void kernel_launch(void* const* d_in, const int* in_sizes, int n_in,
                              void* d_out, int out_size, void* d_ws, size_t ws_size,
                              hipStream_t stream)
{
    const float* x    = (const float*)d_in[0];
    const float* w_q  = (const float*)d_in[1];
    const float* w_k  = (const float*)d_in[2];
    const float* w_v  = (const float*)d_in[3];
    const float* w_qs = (const float*)d_in[4];
    const float* w_ks = (const float*)d_in[5];
    const float* w_vs = (const float*)d_in[6];
    const float* w_qe = (const float*)d_in[7];
    const float* w_ke = (const float*)d_in[8];
    const float* w_ve = (const float*)d_in[9];
    const float* g_m  = (const float*)d_in[10];
    const float* b_m  = (const float*)d_in[11];
    const float* g_s  = (const float*)d_in[12];
    const float* b_s  = (const float*)d_in[13];
    const float* g_e  = (const float*)d_in[14];
    const float* b_e  = (const float*)d_in[15];
    const float* cope = (const float*)d_in[16];

    // fixed buffers
    const size_t n_qk   = (size_t)B_N * T * DK;            // per split buffer
    const size_t fixed  = 4 * n_qk * 2 + n_qk * 2 + (size_t)T * DK * 2;
    // chunk TC: largest of {2560,1280,640,128} fitting ws_size
    auto chunk_bytes = [&](int TC) -> size_t {
        return fixed + (size_t)TC * T * 4 + (size_t)TC * T * 2
                     + (size_t)SS * TC * DK * 4;
    };
    int TC = 128;
    if (chunk_bytes(2560) <= ws_size)      TC = 2560;
    else if (chunk_bytes(1280) <= ws_size) TC = 1280;
    else if (chunk_bytes(640) <= ws_size)  TC = 640;

    char* w = (char*)d_ws;
    __hip_bfloat16* qh    = (__hip_bfloat16*)w; w += n_qk * 2;
    __hip_bfloat16* ql    = (__hip_bfloat16*)w; w += n_qk * 2;
    __hip_bfloat16* kh    = (__hip_bfloat16*)w; w += n_qk * 2;
    __hip_bfloat16* kl    = (__hip_bfloat16*)w; w += n_qk * 2;
    __hip_bfloat16* vT    = (__hip_bfloat16*)w; w += n_qk * 2;
    __hip_bfloat16* copeT = (__hip_bfloat16*)w; w += (size_t)T * DK * 2;
    float*          logc  = (float*)w;          w += (size_t)TC * T * 4;
    __hip_bfloat16* lic   = (__hip_bfloat16*)w; w += (size_t)TC * T * 2;
    float*          part  = (float*)w;

    ln_qkv_kernel<<<(B_N * T) / ROWS_A, 256, 0, stream>>>(
        x, w_q, w_k, w_v, w_qs, w_ks, w_vs, w_qe, w_ke, w_ve,
        g_m, b_m, g_s, b_s, g_e, b_e,
        qh, ql, kh, kl, vT);

    prep_cope_kernel<<<(T * DK) / 256, 256, 0, stream>>>(cope, copeT);

    for (int b = 0; b < B_N; ++b)
        for (int t_off = 0; t_off < T; t_off += TC) {
            gemm1_kernel<<<(TC / 128) * (T / 64), 256, 0, stream>>>(
                qh, ql, kh, kl, copeT, logc, lic, b, t_off);
            phase2_kernel<<<TC, 256, 0, stream>>>(logc, lic, t_off);
            gemm2_kernel<<<(TC / 128) * SS, 256, 0, stream>>>(
                logc, vT, part, b, TC);
            reduce_kernel<<<(TC * DK) / 256, 256, 0, stream>>>(
                part, (float*)d_out, b, t_off, TC);
        }
}

// Round 5
// 141.968 us; speedup vs baseline: 4.8829x; 1.2385x over previous
//
#include <hip/hip_runtime.h>
#include <hip/hip_bf16.h>
#include <math.h>

using short8 = __attribute__((ext_vector_type(8))) short;
using f32x4  = __attribute__((ext_vector_type(4))) float;

constexpr int S_LEN  = 256;
constexpr int T      = 2560;
constexpr int D_IN   = 512;
constexpr int DK     = 64;
constexpr int B_N    = 2;
constexpr int SS     = 16;     // split-K chunks for PV (T/SS = 160 per chunk)

__device__ __forceinline__ float wave_reduce_sum(float v) {
#pragma unroll
    for (int off = 32; off > 0; off >>= 1) v += __shfl_down(v, off);
    return v;
}

// ---------------------------------------------------------------------------
// LN: one row per block; writes xn as split bf16 (hi+lo), row-major 5120x512.
// ---------------------------------------------------------------------------
__global__ __launch_bounds__(256) void ln_kernel(
    const float* __restrict__ x,
    const float* __restrict__ g_m,  const float* __restrict__ b_m,
    const float* __restrict__ g_s,  const float* __restrict__ b_s,
    const float* __restrict__ g_e,  const float* __restrict__ b_e,
    __hip_bfloat16* __restrict__ xnh, __hip_bfloat16* __restrict__ xnl)
{
    const int tid = threadIdx.x;
    const int row = blockIdx.x;
    const int t   = row % T;

    __shared__ float red[4];

    const float *gv, *bv;
    if (t < S_LEN)          { gv = g_s; bv = b_s; }
    else if (t < T - S_LEN) { gv = g_m; bv = b_m; }
    else                    { gv = g_e; bv = b_e; }

    const float* xr = x + (size_t)row * D_IN;
    float a0 = xr[tid], a1 = xr[tid + 256];
    float s = wave_reduce_sum(a0 + a1);
    if ((tid & 63) == 0) red[tid >> 6] = s;
    __syncthreads();
    float mean = (red[0] + red[1] + red[2] + red[3]) * (1.0f / D_IN);
    float d0 = a0 - mean, d1 = a1 - mean;
    float sq = wave_reduce_sum(d0 * d0 + d1 * d1);
    __syncthreads();
    if ((tid & 63) == 0) red[tid >> 6] = sq;
    __syncthreads();
    float var = (red[0] + red[1] + red[2] + red[3]) * (1.0f / D_IN);
    float inv = rsqrtf(var + 1e-5f);

    float v0 = d0 * inv * gv[tid]       + bv[tid];
    float v1 = d1 * inv * gv[tid + 256] + bv[tid + 256];
    __hip_bfloat16 h0 = __float2bfloat16(v0);
    __hip_bfloat16 h1 = __float2bfloat16(v1);
    xnh[(size_t)row * D_IN + tid]       = h0;
    xnh[(size_t)row * D_IN + tid + 256] = h1;
    xnl[(size_t)row * D_IN + tid]       = __float2bfloat16(v0 - __bfloat162float(h0));
    xnl[(size_t)row * D_IN + tid + 256] = __float2bfloat16(v1 - __bfloat162float(h1));
}

// ---------------------------------------------------------------------------
// prep: 9 weight mats (512x64) -> WT[9][64][512] split bf16
// matIdx = region*3 + mat; region0=ss, region1=mid, region2=se
// ---------------------------------------------------------------------------
__global__ __launch_bounds__(256) void prep_wt_kernel(
    const float* __restrict__ w_qs, const float* __restrict__ w_ks, const float* __restrict__ w_vs,
    const float* __restrict__ w_q,  const float* __restrict__ w_k,  const float* __restrict__ w_v,
    const float* __restrict__ w_qe, const float* __restrict__ w_ke, const float* __restrict__ w_ve,
    __hip_bfloat16* __restrict__ wth, __hip_bfloat16* __restrict__ wtl)
{
    const int i = blockIdx.x * 256 + threadIdx.x;     // 9*64*512
    const int matIdx = i >> 15;
    const int rem = i & 32767;
    const int col = rem >> 9, k = rem & 511;
    const float* W =
        (matIdx == 0) ? w_qs : (matIdx == 1) ? w_ks : (matIdx == 2) ? w_vs :
        (matIdx == 3) ? w_q  : (matIdx == 4) ? w_k  : (matIdx == 5) ? w_v  :
        (matIdx == 6) ? w_qe : (matIdx == 7) ? w_ke : w_ve;
    float f = W[(size_t)k * DK + col];
    __hip_bfloat16 h = __float2bfloat16(f);
    wth[i] = h;
    wtl[i] = __float2bfloat16(f - __bfloat162float(h));
}

// cope (DK x T f32) -> copeT (T x DK bf16)
__global__ __launch_bounds__(256) void prep_cope_kernel(
    const float* __restrict__ cope, __hip_bfloat16* __restrict__ copeT)
{
    const int i = blockIdx.x * 256 + threadIdx.x;
    const int m = i >> 6, d = i & 63;
    copeT[i] = __float2bfloat16(cope[(size_t)d * T + m]);
}

// ---------------------------------------------------------------------------
// QKV GEMM: 64-row tile x one matrix (Q/K/V) per block; K=512.
// 3-pass split-bf16 MFMA ~ f32. Emits split q/k and vT bf16.
// ---------------------------------------------------------------------------
__global__ __launch_bounds__(256) void qkv_gemm_kernel(
    const __hip_bfloat16* __restrict__ xnh, const __hip_bfloat16* __restrict__ xnl,
    const __hip_bfloat16* __restrict__ wth, const __hip_bfloat16* __restrict__ wtl,
    __hip_bfloat16* __restrict__ qh, __hip_bfloat16* __restrict__ ql,
    __hip_bfloat16* __restrict__ kh, __hip_bfloat16* __restrict__ kl,
    __hip_bfloat16* __restrict__ vT)
{
    const int bid = blockIdx.x;
    const int mt = bid / 3, mat = bid % 3;
    const int r0 = mt * 64;                    // global row (0..5119)
    const int b  = r0 / T, t0 = r0 % T;
    const int region = (t0 < S_LEN) ? 0 : (t0 < T - S_LEN) ? 1 : 2;
    const int matIdx = region * 3 + mat;

    const int tid = threadIdx.x, lane = tid & 63, wid = tid >> 6;
    const int wm = wid >> 1, wn = wid & 1;
    const int fr = lane & 15, k8 = (lane >> 4) * 8;

    f32x4 acc[2][2];
#pragma unroll
    for (int mf = 0; mf < 2; ++mf)
#pragma unroll
        for (int nf = 0; nf < 2; ++nf) acc[mf][nf] = (f32x4){0.f, 0.f, 0.f, 0.f};

    for (int ks = 0; ks < D_IN / 32; ++ks) {
        const int k = ks * 32 + k8;
        short8 ah[2], al[2], bh2[2], bl2[2];
#pragma unroll
        for (int mf = 0; mf < 2; ++mf) {
            size_t off = (size_t)(r0 + wm * 32 + mf * 16 + fr) * D_IN + k;
            ah[mf] = *(const short8*)(xnh + off);
            al[mf] = *(const short8*)(xnl + off);
        }
#pragma unroll
        for (int nf = 0; nf < 2; ++nf) {
            size_t off = ((size_t)matIdx * DK + wn * 32 + nf * 16 + fr) * D_IN + k;
            bh2[nf] = *(const short8*)(wth + off);
            bl2[nf] = *(const short8*)(wtl + off);
        }
#pragma unroll
        for (int mf = 0; mf < 2; ++mf)
#pragma unroll
            for (int nf = 0; nf < 2; ++nf) {
                acc[mf][nf] = __builtin_amdgcn_mfma_f32_16x16x32_bf16(ah[mf], bh2[nf], acc[mf][nf], 0, 0, 0);
                acc[mf][nf] = __builtin_amdgcn_mfma_f32_16x16x32_bf16(ah[mf], bl2[nf], acc[mf][nf], 0, 0, 0);
                acc[mf][nf] = __builtin_amdgcn_mfma_f32_16x16x32_bf16(al[mf], bh2[nf], acc[mf][nf], 0, 0, 0);
            }
    }

    const int r4 = (lane >> 4) * 4;
#pragma unroll
    for (int mf = 0; mf < 2; ++mf)
#pragma unroll
        for (int nf = 0; nf < 2; ++nf) {
            const int cg = wn * 32 + nf * 16 + fr;
#pragma unroll
            for (int j = 0; j < 4; ++j) {
                const int rg = r0 + wm * 32 + mf * 16 + r4 + j;
                float f = acc[mf][nf][j];
                __hip_bfloat16 h  = __float2bfloat16(f);
                __hip_bfloat16 lo = __float2bfloat16(f - __bfloat162float(h));
                if (mat == 0)      { qh[(size_t)rg * DK + cg] = h; ql[(size_t)rg * DK + cg] = lo; }
                else if (mat == 1) { kh[(size_t)rg * DK + cg] = h; kl[(size_t)rg * DK + cg] = lo; }
                else               { vT[((size_t)b * DK + cg) * T + (rg % T)] = h; }
            }
        }
}

// ---------------------------------------------------------------------------
// GEMM1 (per batch b, chunk of TC rows starting at t_off):
//   logits_c[tl, s] = q.k (split-bf16, 3 passes ~ f32)
//   li_c[tl, s]     = q.cope (bf16)
// ---------------------------------------------------------------------------
__global__ __launch_bounds__(256) void gemm1_kernel(
    const __hip_bfloat16* __restrict__ qh, const __hip_bfloat16* __restrict__ ql,
    const __hip_bfloat16* __restrict__ kh, const __hip_bfloat16* __restrict__ kl,
    const __hip_bfloat16* __restrict__ copeT,
    float* __restrict__ logits_c, __hip_bfloat16* __restrict__ li_c,
    int b, int t_off)
{
    constexpr int TS = T / 64;  // 40
    const int ti  = blockIdx.x / TS, si = blockIdx.x % TS;
    const int t0  = ti * 128, s0 = si * 64;
    const int tid = threadIdx.x, lane = tid & 63, wid = tid >> 6;
    const int wm  = wid >> 1, wn = wid & 1;
    const int fr  = lane & 15, k8 = (lane >> 4) * 8;
    const size_t qb = (size_t)b * T * DK;

    short8 ah[4][2], al[4][2];
#pragma unroll
    for (int mf = 0; mf < 4; ++mf)
#pragma unroll
        for (int ks = 0; ks < 2; ++ks) {
            size_t off = qb + (size_t)(t_off + t0 + wm * 64 + mf * 16 + fr) * DK + ks * 32 + k8;
            ah[mf][ks] = *(const short8*)(qh + off);
            al[mf][ks] = *(const short8*)(ql + off);
        }
    short8 bh[2][2], bl[2][2], bc[2][2];
#pragma unroll
    for (int nf = 0; nf < 2; ++nf)
#pragma unroll
        for (int ks = 0; ks < 2; ++ks) {
            size_t off = (size_t)(s0 + wn * 32 + nf * 16 + fr) * DK + ks * 32 + k8;
            bh[nf][ks] = *(const short8*)(kh + qb + off);
            bl[nf][ks] = *(const short8*)(kl + qb + off);
            bc[nf][ks] = *(const short8*)(copeT + off);
        }

    f32x4 accL[4][2], accM[4][2];
#pragma unroll
    for (int mf = 0; mf < 4; ++mf)
#pragma unroll
        for (int nf = 0; nf < 2; ++nf) {
            accL[mf][nf] = (f32x4){0.f, 0.f, 0.f, 0.f};
            accM[mf][nf] = (f32x4){0.f, 0.f, 0.f, 0.f};
        }

#pragma unroll
    for (int mf = 0; mf < 4; ++mf)
#pragma unroll
        for (int nf = 0; nf < 2; ++nf)
#pragma unroll
            for (int ks = 0; ks < 2; ++ks) {
                accL[mf][nf] = __builtin_amdgcn_mfma_f32_16x16x32_bf16(ah[mf][ks], bh[nf][ks], accL[mf][nf], 0, 0, 0);
                accL[mf][nf] = __builtin_amdgcn_mfma_f32_16x16x32_bf16(ah[mf][ks], bl[nf][ks], accL[mf][nf], 0, 0, 0);
                accL[mf][nf] = __builtin_amdgcn_mfma_f32_16x16x32_bf16(al[mf][ks], bh[nf][ks], accL[mf][nf], 0, 0, 0);
                accM[mf][nf] = __builtin_amdgcn_mfma_f32_16x16x32_bf16(ah[mf][ks], bc[nf][ks], accM[mf][nf], 0, 0, 0);
            }

    const int r4 = (lane >> 4) * 4;
#pragma unroll
    for (int mf = 0; mf < 4; ++mf)
#pragma unroll
        for (int nf = 0; nf < 2; ++nf) {
            const int cg = s0 + wn * 32 + nf * 16 + fr;
#pragma unroll
            for (int j = 0; j < 4; ++j) {
                const int rl = t0 + wm * 64 + mf * 16 + r4 + j;
                const size_t o = (size_t)rl * T + cg;
                logits_c[o] = accL[mf][nf][j];
                li_c[o]     = __float2bfloat16(accM[mf][nf][j]);
            }
        }
}

// ---------------------------------------------------------------------------
// Phase 2 (per chunk): gates -> suffix-sum -> CoPE bias -> softmax.
// Rewrites logits_c row IN PLACE with normalized p (f32).
// ---------------------------------------------------------------------------
__global__ __launch_bounds__(256) void phase2_kernel(
    float* __restrict__ logits_c, const __hip_bfloat16* __restrict__ li_c,
    int t_off)
{
    const int tid = threadIdx.x;
    const int rl  = blockIdx.x;
    const int t   = t_off + rl;

    __shared__ float          slog[T];
    __shared__ __hip_bfloat16 sli[T];
    __shared__ float          sscan[256];
    __shared__ float          red[8];

    float*                lrow  = logits_c + (size_t)rl * T;
    const __hip_bfloat16* lirow = li_c     + (size_t)rl * T;
#pragma unroll
    for (int i = 0; i < 10; ++i) slog[i * 256 + tid] = lrow[i * 256 + tid];
#pragma unroll
    for (int i = 0; i < 10; ++i) sli[i * 256 + tid] = lirow[i * 256 + tid];
    __syncthreads();

    constexpr int CH = T / 256;  // 10
    const int s0 = tid * CH;
    float g[CH];
    float lsum = 0.f;
#pragma unroll
    for (int i = 0; i < CH; ++i) {
        g[i] = 1.0f / (1.0f + __expf(-slog[s0 + i]));
        lsum += g[i];
    }
    sscan[tid] = lsum;
    __syncthreads();
    for (int off = 1; off < 256; off <<= 1) {
        float add = (tid >= off) ? sscan[tid - off] : 0.f;
        __syncthreads();
        sscan[tid] += add;
        __syncthreads();
    }
    const float total = sscan[255];
    float run = sscan[tid] - lsum;

    float att[CH];
    float lmax = -INFINITY;
#pragma unroll
    for (int i = 0; i < CH; ++i) {
        int s = s0 + i;
        float pos = total - run;
        run += g[i];
        pos = fminf(pos, (float)(T - 1));
        float pf = floorf(pos);
        float w  = pos - pf;
        int ipf  = (int)pf;
        int ipc  = (int)ceilf(pos);
        float bias = __bfloat162float(sli[ipc]) * w
                   + __bfloat162float(sli[ipf]) * (1.0f - w);
        float al = slog[s] * 0.125f + bias;
        if (s > t) al = -INFINITY;
        att[i] = al;
        lmax = fmaxf(lmax, al);
    }

#pragma unroll
    for (int off = 32; off > 0; off >>= 1) lmax = fmaxf(lmax, __shfl_down(lmax, off));
    __syncthreads();
    if ((tid & 63) == 0) red[tid >> 6] = lmax;
    __syncthreads();
    const float bmax = fmaxf(fmaxf(red[0], red[1]), fmaxf(red[2], red[3]));

    float e[CH];
    float esum = 0.f;
#pragma unroll
    for (int i = 0; i < CH; ++i) {
        e[i] = __expf(att[i] - bmax);
        esum += e[i];
    }
#pragma unroll
    for (int off = 32; off > 0; off >>= 1) esum += __shfl_down(esum, off);
    __syncthreads();
    if ((tid & 63) == 0) red[4 + (tid >> 6)] = esum;
    __syncthreads();
    const float rden = 1.0f / (red[4] + red[5] + red[6] + red[7]);

#pragma unroll
    for (int i = 0; i < CH; ++i)
        lrow[s0 + i] = e[i] * rden;
}

// ---------------------------------------------------------------------------
// GEMM2 (per chunk): out_part = P @ V, split-K into SS chunks of 160.
// ---------------------------------------------------------------------------
__global__ __launch_bounds__(256) void gemm2_kernel(
    const float* __restrict__ p_c, const __hip_bfloat16* __restrict__ vT,
    float* __restrict__ part, int b, int TC)
{
    const int ti  = blockIdx.x / SS, sc = blockIdx.x % SS;
    const int t0  = ti * 128;
    const int sb  = sc * (T / SS);
    const int tid = threadIdx.x, lane = tid & 63, wid = tid >> 6;
    const int wm  = wid >> 1, wn = wid & 1;
    const int fr  = lane & 15, k8 = (lane >> 4) * 8;
    const size_t vb = (size_t)b * DK * T;

    f32x4 acc[4][2];
#pragma unroll
    for (int mf = 0; mf < 4; ++mf)
#pragma unroll
        for (int nf = 0; nf < 2; ++nf) acc[mf][nf] = (f32x4){0.f, 0.f, 0.f, 0.f};

    for (int ks = 0; ks < (T / SS) / 32; ++ks) {
        const int s = sb + ks * 32 + k8;
        short8 a_h[4], a_l[4], bv[2];
#pragma unroll
        for (int mf = 0; mf < 4; ++mf) {
            const float* pp = p_c + (size_t)(t0 + wm * 64 + mf * 16 + fr) * T + s;
            short hh[8], ll[8];
#pragma unroll
            for (int j = 0; j < 8; ++j) {
                float p = pp[j];
                __hip_bfloat16 h  = __float2bfloat16(p);
                __hip_bfloat16 lo = __float2bfloat16(p - __bfloat162float(h));
                hh[j] = *(short*)&h;
                ll[j] = *(short*)&lo;
            }
            a_h[mf] = (short8){hh[0],hh[1],hh[2],hh[3],hh[4],hh[5],hh[6],hh[7]};
            a_l[mf] = (short8){ll[0],ll[1],ll[2],ll[3],ll[4],ll[5],ll[6],ll[7]};
        }
#pragma unroll
        for (int nf = 0; nf < 2; ++nf)
            bv[nf] = *(const short8*)(vT + vb + (size_t)(wn * 32 + nf * 16 + fr) * T + s);
#pragma unroll
        for (int mf = 0; mf < 4; ++mf)
#pragma unroll
            for (int nf = 0; nf < 2; ++nf) {
                acc[mf][nf] = __builtin_amdgcn_mfma_f32_16x16x32_bf16(a_h[mf], bv[nf], acc[mf][nf], 0, 0, 0);
                acc[mf][nf] = __builtin_amdgcn_mfma_f32_16x16x32_bf16(a_l[mf], bv[nf], acc[mf][nf], 0, 0, 0);
            }
    }

    const int r4 = (lane >> 4) * 4;
#pragma unroll
    for (int mf = 0; mf < 4; ++mf)
#pragma unroll
        for (int nf = 0; nf < 2; ++nf) {
            const int cg = wn * 32 + nf * 16 + fr;
#pragma unroll
            for (int j = 0; j < 4; ++j) {
                const int rl = t0 + wm * 64 + mf * 16 + r4 + j;
                part[((size_t)sc * TC + rl) * DK + cg] = acc[mf][nf][j];
            }
        }
}

__global__ __launch_bounds__(256) void reduce_kernel(
    const float* __restrict__ part, float* __restrict__ out,
    int b, int t_off, int TC)
{
    const size_t i = (size_t)blockIdx.x * 256 + threadIdx.x;
    float s = 0.f;
    for (int sc = 0; sc < SS; ++sc) s += part[(size_t)sc * TC * DK + i];
    out[((size_t)b * T + t_off) * DK + i] = s;
}

extern "C" void kernel_launch(void* const* d_in, const int* in_sizes, int n_in,
                              void* d_out, int out_size, void* d_ws, size_t ws_size,
                              hipStream_t stream)
{
    const float* x    = (const float*)d_in[0];
    const float* w_q  = (const float*)d_in[1];
    const float* w_k  = (const float*)d_in[2];
    const float* w_v  = (const float*)d_in[3];
    const float* w_qs = (const float*)d_in[4];
    const float* w_ks = (const float*)d_in[5];
    const float* w_vs = (const float*)d_in[6];
    const float* w_qe = (const float*)d_in[7];
    const float* w_ke = (const float*)d_in[8];
    const float* w_ve = (const float*)d_in[9];
    const float* g_m  = (const float*)d_in[10];
    const float* b_m  = (const float*)d_in[11];
    const float* g_s  = (const float*)d_in[12];
    const float* b_s  = (const float*)d_in[13];
    const float* g_e  = (const float*)d_in[14];
    const float* b_e  = (const float*)d_in[15];
    const float* cope = (const float*)d_in[16];

    const size_t n_qk  = (size_t)B_N * T * DK;
    const size_t n_xn  = (size_t)B_N * T * D_IN;
    const size_t n_wt  = (size_t)9 * DK * D_IN;
    const size_t fixed = 5 * n_qk * 2 + (size_t)T * DK * 2
                       + 2 * n_xn * 2 + 2 * n_wt * 2;
    auto chunk_bytes = [&](int TC) -> size_t {
        return fixed + (size_t)TC * T * 4 + (size_t)TC * T * 2
                     + (size_t)SS * TC * DK * 4;
    };
    int TC = 128;
    if (chunk_bytes(2560) <= ws_size)      TC = 2560;
    else if (chunk_bytes(1280) <= ws_size) TC = 1280;
    else if (chunk_bytes(640) <= ws_size)  TC = 640;

    char* w = (char*)d_ws;
    __hip_bfloat16* qh    = (__hip_bfloat16*)w; w += n_qk * 2;
    __hip_bfloat16* ql    = (__hip_bfloat16*)w; w += n_qk * 2;
    __hip_bfloat16* kh    = (__hip_bfloat16*)w; w += n_qk * 2;
    __hip_bfloat16* kl    = (__hip_bfloat16*)w; w += n_qk * 2;
    __hip_bfloat16* vT    = (__hip_bfloat16*)w; w += n_qk * 2;
    __hip_bfloat16* copeT = (__hip_bfloat16*)w; w += (size_t)T * DK * 2;
    __hip_bfloat16* xnh   = (__hip_bfloat16*)w; w += n_xn * 2;
    __hip_bfloat16* xnl   = (__hip_bfloat16*)w; w += n_xn * 2;
    __hip_bfloat16* wth   = (__hip_bfloat16*)w; w += n_wt * 2;
    __hip_bfloat16* wtl   = (__hip_bfloat16*)w; w += n_wt * 2;
    float*          logc  = (float*)w;          w += (size_t)TC * T * 4;
    __hip_bfloat16* lic   = (__hip_bfloat16*)w; w += (size_t)TC * T * 2;
    float*          part  = (float*)w;

    ln_kernel<<<B_N * T, 256, 0, stream>>>(
        x, g_m, b_m, g_s, b_s, g_e, b_e, xnh, xnl);

    prep_wt_kernel<<<(int)(n_wt / 256), 256, 0, stream>>>(
        w_qs, w_ks, w_vs, w_q, w_k, w_v, w_qe, w_ke, w_ve, wth, wtl);

    prep_cope_kernel<<<(T * DK) / 256, 256, 0, stream>>>(cope, copeT);

    qkv_gemm_kernel<<<(B_N * T / 64) * 3, 256, 0, stream>>>(
        xnh, xnl, wth, wtl, qh, ql, kh, kl, vT);

    for (int b = 0; b < B_N; ++b)
        for (int t_off = 0; t_off < T; t_off += TC) {
            gemm1_kernel<<<(TC / 128) * (T / 64), 256, 0, stream>>>(
                qh, ql, kh, kl, copeT, logc, lic, b, t_off);
            phase2_kernel<<<TC, 256, 0, stream>>>(logc, lic, t_off);
            gemm2_kernel<<<(TC / 128) * SS, 256, 0, stream>>>(
                logc, vT, part, b, TC);
            reduce_kernel<<<(TC * DK) / 256, 256, 0, stream>>>(
                part, (float*)d_out, b, t_off, TC);
        }
}